// Round 9
// baseline (390.004 us; speedup 1.0000x reference)
//
#include <hip/hip_runtime.h>
#include <stdint.h>

#define NB   8
#define TOK  4096
#define DIM  512
#define HALF 2048
#define RR   1024

typedef unsigned long long u64;
typedef unsigned int u32;
typedef _Float16 f16;
typedef f16 f16x4 __attribute__((ext_vector_type(4)));
typedef f16 f16x8 __attribute__((ext_vector_type(8)));
typedef float f32x4 __attribute__((ext_vector_type(4)));

#define AS1 __attribute__((address_space(1)))
#define AS3 __attribute__((address_space(3)))
#define GLL16(GP, LP) __builtin_amdgcn_global_load_lds((const AS1 u32*)(GP), (AS3 u32*)(LP), 16, 0, 0)

__device__ __forceinline__ u32 mono_f32(float f) {
    u32 u = __float_as_uint(f);
    return (u & 0x80000000u) ? ~u : (u | 0x80000000u);
}
__device__ __forceinline__ u64 umax64(u64 a, u64 b) { return a > b ? a : b; }

// ---------------- merged preprocessing: prep (split+norms) | wsplit | init ----------------
__global__ void k_pre(const float* __restrict__ x, f16* __restrict__ xh, f16* __restrict__ xl,
                      float* __restrict__ invn, const float* __restrict__ W,
                      f16* __restrict__ Wh, f16* __restrict__ Wl,
                      u64* __restrict__ best, u64* __restrict__ wkey) {
    __shared__ float tile[64][65];
    int bid = blockIdx.x, tid = threadIdx.x;
    if (bid < 8192) {
        // split x -> fp16 hi/lo + inverse norms
        int row  = bid * 4 + (tid >> 6);
        int lane = tid & 63;
        const float* p = x + (size_t)row * DIM + 4 * lane;
        float4 v0 = *(const float4*)p;
        float4 v1 = *(const float4*)(p + 256);
        float va[8] = {v0.x, v0.y, v0.z, v0.w, v1.x, v1.y, v1.z, v1.w};
        f16x4 h0, h1, l0, l1;
#pragma unroll
        for (int e = 0; e < 4; ++e) {
            f16 hh = (f16)va[e];     h0[e] = hh;  l0[e] = (f16)(va[e] - (float)hh);
            f16 hh1 = (f16)va[e+4];  h1[e] = hh1; l1[e] = (f16)(va[e+4] - (float)hh1);
        }
        size_t off = (size_t)row * DIM + 4 * lane;
        *(f16x4*)(xh + off)       = h0;
        *(f16x4*)(xh + off + 256) = h1;
        *(f16x4*)(xl + off)       = l0;
        *(f16x4*)(xl + off + 256) = l1;
        float ss = va[0]*va[0] + va[1]*va[1] + va[2]*va[2] + va[3]*va[3]
                 + va[4]*va[4] + va[5]*va[5] + va[6]*va[6] + va[7]*va[7];
#pragma unroll
        for (int m = 32; m; m >>= 1) ss += __shfl_xor(ss, m, 64);
        if (lane == 0) invn[row] = 1.0f / fmaxf(sqrtf(ss), 1e-12f);
    } else if (bid < 8256) {
        // split + transpose W -> [n][k]
        int wb = bid - 8192;
        int k0 = (wb >> 3) * 64, n0 = (wb & 7) * 64;
#pragma unroll
        for (int i = 0; i < 16; ++i) {
            int idx = tid + 256 * i;
            int r = idx >> 6, c = idx & 63;
            tile[r][c] = W[(size_t)(k0 + r) * DIM + n0 + c];
        }
        __syncthreads();
#pragma unroll
        for (int i = 0; i < 16; ++i) {
            int idx = tid + 256 * i;
            int n = idx >> 6, k = idx & 63;
            float v = tile[k][n];
            f16 h = (f16)v;
            Wh[(size_t)(n0 + n) * DIM + k0 + k] = h;
            Wl[(size_t)(n0 + n) * DIM + k0 + k] = (f16)(v - (float)h);
        }
    } else {
        int i = (bid - 8256) * 256 + tid;
        if (i < NB * HALF) { best[i] = 0ull; wkey[i] = ~0ull; }
    }
}

// ======== fused-thirds 128x128 GEMM core, 2-phase prefetch, LDS dbuf ========
// LDS: 2 buffers x 4 quarters [128][64] f16 (Ah|Al|Bh|Bl) = 128 KB, XOR-swizzled
// (granule g: row m=g>>3, slot s=g&7 holds chunk s^(m&7); read chunk ch at slot ch^(m&7)).
// Per K-step: issue next tile's 16 GLL16 -> OTHER buffer, then ds_read+MFMA current,
// then ONE __syncthreads() (implicit vmcnt(0) drain lands ~470 MFMA-cycles after issue).

#define STAGE4(AP, BP, LB, COL) { \
  _Pragma("unroll") for (int r_ = 0; r_ < 4; ++r_) { \
    size_t d_ = (size_t)(256 * r_ + 64 * w) * 8; \
    GLL16((AP##h) + rowA[r_] + (COL), (LB) + d_); \
    GLL16((AP##l) + rowA[r_] + (COL), (LB) + 8192 + d_); \
    GLL16((BP##h) + rowB[r_] + (COL), (LB) + 16384 + d_); \
    GLL16((BP##l) + rowB[r_] + (COL), (LB) + 24576 + d_); \
  } }

#define COMPUTE_STEP(LB) { \
  const f16* Ah_ = (LB) + (wr * 64 + rm) * 64; \
  const f16* Bh_ = (LB) + 16384 + (wc * 64 + rm) * 64; \
  _Pragma("unroll") for (int kk = 0; kk < 2; ++kk) { \
    int ex = 8 * ((kk * 4 + cc) ^ rm7); \
    f16x8 ah[4], al[4], bh[4], bl[4]; \
    _Pragma("unroll") for (int f = 0; f < 4; ++f) { \
      ah[f] = *(const f16x8*)(Ah_ + f * 1024 + ex); \
      al[f] = *(const f16x8*)(Ah_ + 8192 + f * 1024 + ex); \
      bh[f] = *(const f16x8*)(Bh_ + f * 1024 + ex); \
      bl[f] = *(const f16x8*)(Bh_ + 8192 + f * 1024 + ex); \
    } \
    _Pragma("unroll") for (int i = 0; i < 4; ++i) \
      _Pragma("unroll") for (int j = 0; j < 4; ++j) { \
        acc[i][j] = __builtin_amdgcn_mfma_f32_16x16x32_f16(ah[i], bh[j], acc[i][j], 0, 0, 0); \
        acc[i][j] = __builtin_amdgcn_mfma_f32_16x16x32_f16(al[i], bh[j], acc[i][j], 0, 0, 0); \
        acc[i][j] = __builtin_amdgcn_mfma_f32_16x16x32_f16(ah[i], bl[j], acc[i][j], 0, 0, 0); \
      } \
  } }

// ---------------- scores GEMM + fused row argmax ----------------
__launch_bounds__(256)
__global__ void k_scores(const f16* __restrict__ xh, const f16* __restrict__ xl,
                         const float* __restrict__ invn, u64* __restrict__ best) {
    __shared__ __align__(16) f16 L[2][4][128][64];   // 128 KB
    int bx = blockIdx.x;
    int b = bx >> 8, sb = (bx >> 4) & 15, tb = bx & 15;
    int tid = threadIdx.x, lane = tid & 63, w = tid >> 6, wr = w >> 1, wc = w & 1;
    int cc = lane >> 4, rm = lane & 15, rm7 = rm & 7;
    f16* L0 = &L[0][0][0][0];
    f16* L1 = &L[1][0][0][0];

    f32x4 acc[4][4];
#pragma unroll
    for (int i = 0; i < 4; ++i)
#pragma unroll
        for (int j = 0; j < 4; ++j) acc[i][j] = (f32x4){0.f, 0.f, 0.f, 0.f};

    size_t rowA[4], rowB[4];
#pragma unroll
    for (int r = 0; r < 4; ++r) {
        int g = tid + 256 * r;
        int m = g >> 3;
        int chunk = (g & 7) ^ (m & 7);
        rowA[r] = ((size_t)b * TOK + 2 * (sb * 128 + m) + 1) * DIM + 8 * chunk;
        rowB[r] = ((size_t)b * TOK + 2 * (tb * 128 + m)    ) * DIM + 8 * chunk;
    }

    STAGE4(x, x, L0, 0)
    __syncthreads();
#pragma unroll 1
    for (int ks = 0; ks < 8; ++ks) {
        f16* Lc = (ks & 1) ? L1 : L0;
        f16* Ln = (ks & 1) ? L0 : L1;
        if (ks < 7) { int coln = (ks + 1) << 6; STAGE4(x, x, Ln, coln) }
        COMPUTE_STEP(Lc)
        __syncthreads();
    }

    float invd[4];
#pragma unroll
    for (int j = 0; j < 4; ++j) {
        int t = tb * 128 + wc * 64 + j * 16 + rm;
        invd[j] = invn[(size_t)b * TOK + 2 * t];
    }
#pragma unroll
    for (int i = 0; i < 4; ++i) {
#pragma unroll
        for (int r = 0; r < 4; ++r) {
            int s = sb * 128 + wr * 64 + i * 16 + cc * 4 + r;   // C row = (lane>>4)*4 + reg
            float invs = invn[(size_t)b * TOK + 2 * s + 1];
            u64 key = 0;
#pragma unroll
            for (int j = 0; j < 4; ++j) {
                int t = tb * 128 + wc * 64 + j * 16 + rm;       // C col = lane&15
                float sc = acc[i][j][r] * invs * invd[j];
                u64 k = ((u64)mono_f32(sc) << 32) | (u32)(2047 - t);
                key = umax64(key, k);
            }
#pragma unroll
            for (int m = 1; m < 16; m <<= 1) {
                u32 lo = (u32)key, hi = (u32)(key >> 32);
                lo = __shfl_xor(lo, m, 64);
                hi = __shfl_xor(hi, m, 64);
                key = umax64(key, ((u64)hi << 32) | lo);
            }
            if (rm == 0) atomicMax(&best[b * HALF + s], key);
        }
    }
}

// ---------------- top-k + duplicate-dst winner ----------------
__global__ void k_topk(const u64* __restrict__ best, u64* __restrict__ wkey,
                       u32* __restrict__ member, u32* __restrict__ dstmap) {
    __shared__ u32 smono[HALF];
    int b = blockIdx.x >> 4, sc = blockIdx.x & 15;
    int tid = threadIdx.x;
#pragma unroll
    for (int r = 0; r < 8; ++r) { int s = r * 256 + tid; smono[s] = (u32)(best[b * HALF + s] >> 32); }
    __syncthreads();
    int s = sc * 128 + (tid >> 1);
    u32 ms = smono[s];
    int t0 = (tid & 1) * 1024;
    int cnt = 0;
    for (int t = t0; t < t0 + 1024; ++t) {
        u32 mt = smono[t];
        cnt += ((mt > ms) || (mt == ms && t < s)) ? 1 : 0;
    }
    int oth = __shfl_xor(cnt, 1, 64);
    if ((tid & 1) == 0) {
        int rank = cnt + oth;
        u64 k = best[b * HALF + s];
        u32 d = 2047u - (u32)(k & 0xffffffffu);
        dstmap[b * HALF + s] = d;
        u32 mem = (rank < RR) ? 1u : 0u;
        member[b * HALF + s] = mem;
        if (mem) {
            u64 key = (k & 0xffffffff00000000ull) | (u32)(2047 - s);
            atomicMin(&wkey[b * HALF + d], key);   // last-wins: lowest score, then largest s
        }
    }
}

// ---------------- merged dst rows -> split((dst+src)/2) ----------------
__global__ void k_merge2(const float* __restrict__ x, const u64* __restrict__ wkey,
                         f16* __restrict__ xh, f16* __restrict__ xl) {
    int idx = blockIdx.x;
    int b = idx >> 11, d = idx & (HALF - 1);
    u64 wk = wkey[b * HALF + d];
    if (wk == ~0ull) return;
    int s = 2047 - (int)(wk & 0xffffffffu);
    const float* xd = x + ((size_t)b * TOK + 2 * d) * DIM;
    const float* xs = x + ((size_t)b * TOK + 2 * s + 1) * DIM;
    int l0 = threadIdx.x * 8;
    f16x8 h, l;
#pragma unroll
    for (int e = 0; e < 8; ++e) {
        float v = (xd[l0 + e] + xs[l0 + e]) * 0.5f;
        f16 hh = (f16)v;
        h[e] = hh;
        l[e] = (f16)(v - (float)hh);
    }
    size_t off = ((size_t)b * TOK + 2 * d) * DIM + l0;
    *(f16x8*)(xh + off) = h;
    *(f16x8*)(xl + off) = l;
}

// ---------------- y = x_merged @ W + b  (merged-away src rows remapped to their dst) ----------------
__launch_bounds__(256)
__global__ void k_out(const f16* __restrict__ xh, const f16* __restrict__ xl,
                      const f16* __restrict__ Wh, const f16* __restrict__ Wl,
                      const float* __restrict__ bias, const u32* __restrict__ member,
                      const u32* __restrict__ dstmap, float* __restrict__ out) {
    __shared__ __align__(16) f16 L[2][4][128][64];   // 128 KB
    int bx = blockIdx.x;
    int im = bx >> 2, in = bx & 3;
    int tid = threadIdx.x, lane = tid & 63, w = tid >> 6, wr = w >> 1, wc = w & 1;
    int cc = lane >> 4, rm = lane & 15, rm7 = rm & 7;
    f16* L0 = &L[0][0][0][0];
    f16* L1 = &L[1][0][0][0];

    f32x4 acc[4][4];
#pragma unroll
    for (int i = 0; i < 4; ++i)
#pragma unroll
        for (int j = 0; j < 4; ++j) acc[i][j] = (f32x4){0.f, 0.f, 0.f, 0.f};

    size_t rowA[4], rowB[4];
#pragma unroll
    for (int r = 0; r < 4; ++r) {
        int g = tid + 256 * r;
        int m = g >> 3;
        int chunk = (g & 7) ^ (m & 7);
        int grow = im * 128 + m;
        int b_ = grow >> 12, tok = grow & (TOK - 1);
        // merged-away src row: stage its dst's merged x instead (result == dvals copy)
        if (tok & 1) {
            int s = tok >> 1;
            if (member[b_ * HALF + s]) tok = 2 * (int)dstmap[b_ * HALF + s];
        }
        rowA[r] = (((size_t)b_ << 12) + tok) * DIM + 8 * chunk;
        rowB[r] = (size_t)(in * 128 + m) * DIM + 8 * chunk;
    }

    STAGE4(x, W, L0, 0)
    __syncthreads();
#pragma unroll 1
    for (int ks = 0; ks < 8; ++ks) {
        f16* Lc = (ks & 1) ? L1 : L0;
        f16* Ln = (ks & 1) ? L0 : L1;
        if (ks < 7) { int coln = (ks + 1) << 6; STAGE4(x, W, Ln, coln) }
        COMPUTE_STEP(Lc)
        __syncthreads();
    }

    float bj[4];
#pragma unroll
    for (int j = 0; j < 4; ++j) bj[j] = bias[in * 128 + wc * 64 + j * 16 + rm];
#pragma unroll
    for (int i = 0; i < 4; ++i) {
#pragma unroll
        for (int r = 0; r < 4; ++r) {
            int gm = im * 128 + wr * 64 + i * 16 + cc * 4 + r;
#pragma unroll
            for (int j = 0; j < 4; ++j) {
                int n = in * 128 + wc * 64 + j * 16 + rm;
                out[(size_t)gm * DIM + n] = acc[i][j][r] + bj[j];
            }
        }
    }
}

extern "C" void kernel_launch(void* const* d_in, const int* in_sizes, int n_in,
                              void* d_out, int out_size, void* d_ws, size_t ws_size,
                              hipStream_t stream) {
    const float* x    = (const float*)d_in[0];
    const float* W    = (const float*)d_in[1];
    const float* bias = (const float*)d_in[2];
    float* out = (float*)d_out;

    char* ws = (char*)d_ws;
    f16*   xh     = (f16*)(ws);                               // 32 MB
    f16*   xl     = (f16*)(ws + (32u << 20));                 // 32 MB
    f16*   Wh     = (f16*)(ws + (64u << 20));                 // 512 KB
    f16*   Wl     = (f16*)(ws + (64u << 20) + (512u << 10));  // 512 KB
    float* invn   = (float*)(ws + (65u << 20));               // 128 KB
    u64*   best   = (u64*)(ws + (65u << 20) + (128u << 10));  // 128 KB
    u64*   wkey   = (u64*)(ws + (65u << 20) + (256u << 10));  // 128 KB
    u32*   dstmap = (u32*)(ws + (65u << 20) + (384u << 10));  //  64 KB
    u32*   member = (u32*)(ws + (65u << 20) + (448u << 10));  //  64 KB

    hipLaunchKernelGGL(k_pre,    dim3(8320),  dim3(256), 0, stream, x, xh, xl, invn, W, Wh, Wl, best, wkey);
    hipLaunchKernelGGL(k_scores, dim3(2048),  dim3(256), 0, stream, xh, xl, invn, best);
    hipLaunchKernelGGL(k_topk,   dim3(128),   dim3(256), 0, stream, best, wkey, member, dstmap);
    hipLaunchKernelGGL(k_merge2, dim3(16384), dim3(64),  0, stream, x, wkey, xh, xl);
    hipLaunchKernelGGL(k_out,    dim3(1024),  dim3(256), 0, stream, xh, xl, Wh, Wl, bias, member, dstmap, out);
}

// Round 10
// 331.373 us; speedup vs baseline: 1.1769x; 1.1769x over previous
//
#include <hip/hip_runtime.h>
#include <stdint.h>

#define NB   8
#define TOK  4096
#define DIM  512
#define HALF 2048
#define RR   1024

typedef unsigned long long u64;
typedef unsigned int u32;
typedef _Float16 f16;
typedef f16 f16x4 __attribute__((ext_vector_type(4)));
typedef f16 f16x8 __attribute__((ext_vector_type(8)));
typedef float f32x4 __attribute__((ext_vector_type(4)));

#define AS1 __attribute__((address_space(1)))
#define AS3 __attribute__((address_space(3)))
#define GLL16(GP, LP) __builtin_amdgcn_global_load_lds((const AS1 u32*)(GP), (AS3 u32*)(LP), 16, 0, 0)

__device__ __forceinline__ u32 mono_f32(float f) {
    u32 u = __float_as_uint(f);
    return (u & 0x80000000u) ? ~u : (u | 0x80000000u);
}
__device__ __forceinline__ u64 umax64(u64 a, u64 b) { return a > b ? a : b; }

// ---------------- merged preprocessing: prep (split+norms) | wsplit | init ----------------
__global__ void k_pre(const float* __restrict__ x, f16* __restrict__ xh, f16* __restrict__ xl,
                      float* __restrict__ invn, const float* __restrict__ W,
                      f16* __restrict__ Wh, f16* __restrict__ Wl,
                      u64* __restrict__ best, u64* __restrict__ wkey) {
    __shared__ float tile[64][65];
    int bid = blockIdx.x, tid = threadIdx.x;
    if (bid < 8192) {
        // split x -> fp16 hi/lo + inverse norms
        int row  = bid * 4 + (tid >> 6);
        int lane = tid & 63;
        const float* p = x + (size_t)row * DIM + 4 * lane;
        float4 v0 = *(const float4*)p;
        float4 v1 = *(const float4*)(p + 256);
        float va[8] = {v0.x, v0.y, v0.z, v0.w, v1.x, v1.y, v1.z, v1.w};
        f16x4 h0, h1, l0, l1;
#pragma unroll
        for (int e = 0; e < 4; ++e) {
            f16 hh = (f16)va[e];     h0[e] = hh;  l0[e] = (f16)(va[e] - (float)hh);
            f16 hh1 = (f16)va[e+4];  h1[e] = hh1; l1[e] = (f16)(va[e+4] - (float)hh1);
        }
        size_t off = (size_t)row * DIM + 4 * lane;
        *(f16x4*)(xh + off)       = h0;
        *(f16x4*)(xh + off + 256) = h1;
        *(f16x4*)(xl + off)       = l0;
        *(f16x4*)(xl + off + 256) = l1;
        float ss = va[0]*va[0] + va[1]*va[1] + va[2]*va[2] + va[3]*va[3]
                 + va[4]*va[4] + va[5]*va[5] + va[6]*va[6] + va[7]*va[7];
#pragma unroll
        for (int m = 32; m; m >>= 1) ss += __shfl_xor(ss, m, 64);
        if (lane == 0) invn[row] = 1.0f / fmaxf(sqrtf(ss), 1e-12f);
    } else if (bid < 8256) {
        // split + transpose W -> [n][k]
        int wb = bid - 8192;
        int k0 = (wb >> 3) * 64, n0 = (wb & 7) * 64;
#pragma unroll
        for (int i = 0; i < 16; ++i) {
            int idx = tid + 256 * i;
            int r = idx >> 6, c = idx & 63;
            tile[r][c] = W[(size_t)(k0 + r) * DIM + n0 + c];
        }
        __syncthreads();
#pragma unroll
        for (int i = 0; i < 16; ++i) {
            int idx = tid + 256 * i;
            int n = idx >> 6, k = idx & 63;
            float v = tile[k][n];
            f16 h = (f16)v;
            Wh[(size_t)(n0 + n) * DIM + k0 + k] = h;
            Wl[(size_t)(n0 + n) * DIM + k0 + k] = (f16)(v - (float)h);
        }
    } else {
        int i = (bid - 8256) * 256 + tid;
        if (i < NB * HALF) { best[i] = 0ull; wkey[i] = ~0ull; }
    }
}

// ======== fused-thirds 128x128 GEMM core (round-8 proven structure) ========
// LDS: 4 quarters [128][64] f16 (Ah|Al|Bh|Bl) = 64 KB -> 2 blocks/CU, XOR-swizzled
// (granule g: row m=g>>3, slot s=g&7 holds chunk s^(m&7); read chunk ch at slot ch^(m&7)).
// Per physical K-chunk of 64: stage 16 GLL16/thread, barrier (drains vmcnt),
// 96 MFMA : 32 ds_read per wave (acc += ah*bh + al*bh + ah*bl), barrier.

#define STAGE4(AP, BP, LB, COL) { \
  _Pragma("unroll") for (int r_ = 0; r_ < 4; ++r_) { \
    size_t d_ = (size_t)(256 * r_ + 64 * w) * 8; \
    GLL16((AP##h) + rowA[r_] + (COL), (LB) + d_); \
    GLL16((AP##l) + rowA[r_] + (COL), (LB) + 8192 + d_); \
    GLL16((BP##h) + rowB[r_] + (COL), (LB) + 16384 + d_); \
    GLL16((BP##l) + rowB[r_] + (COL), (LB) + 24576 + d_); \
  } }

#define COMPUTE_STEP(LB) { \
  const f16* Ah_ = (LB) + (wr * 64 + rm) * 64; \
  const f16* Bh_ = (LB) + 16384 + (wc * 64 + rm) * 64; \
  _Pragma("unroll") for (int kk = 0; kk < 2; ++kk) { \
    int ex = 8 * ((kk * 4 + cc) ^ rm7); \
    f16x8 ah[4], al[4], bh[4], bl[4]; \
    _Pragma("unroll") for (int f = 0; f < 4; ++f) { \
      ah[f] = *(const f16x8*)(Ah_ + f * 1024 + ex); \
      al[f] = *(const f16x8*)(Ah_ + 8192 + f * 1024 + ex); \
      bh[f] = *(const f16x8*)(Bh_ + f * 1024 + ex); \
      bl[f] = *(const f16x8*)(Bh_ + 8192 + f * 1024 + ex); \
    } \
    _Pragma("unroll") for (int i = 0; i < 4; ++i) \
      _Pragma("unroll") for (int j = 0; j < 4; ++j) { \
        acc[i][j] = __builtin_amdgcn_mfma_f32_16x16x32_f16(ah[i], bh[j], acc[i][j], 0, 0, 0); \
        acc[i][j] = __builtin_amdgcn_mfma_f32_16x16x32_f16(al[i], bh[j], acc[i][j], 0, 0, 0); \
        acc[i][j] = __builtin_amdgcn_mfma_f32_16x16x32_f16(ah[i], bl[j], acc[i][j], 0, 0, 0); \
      } \
  } }

// ---------------- scores GEMM + fused row argmax ----------------
__launch_bounds__(256, 2)
__global__ void k_scores(const f16* __restrict__ xh, const f16* __restrict__ xl,
                         const float* __restrict__ invn, u64* __restrict__ best) {
    __shared__ __align__(16) f16 L[4][128][64];   // 64 KB
    int bx = blockIdx.x;
    int b = bx >> 8, sb = (bx >> 4) & 15, tb = bx & 15;
    int tid = threadIdx.x, lane = tid & 63, w = tid >> 6, wr = w >> 1, wc = w & 1;
    int cc = lane >> 4, rm = lane & 15, rm7 = rm & 7;
    f16* L0 = &L[0][0][0];

    f32x4 acc[4][4];
#pragma unroll
    for (int i = 0; i < 4; ++i)
#pragma unroll
        for (int j = 0; j < 4; ++j) acc[i][j] = (f32x4){0.f, 0.f, 0.f, 0.f};

    size_t rowA[4], rowB[4];
#pragma unroll
    for (int r = 0; r < 4; ++r) {
        int g = tid + 256 * r;
        int m = g >> 3;
        int chunk = (g & 7) ^ (m & 7);
        rowA[r] = ((size_t)b * TOK + 2 * (sb * 128 + m) + 1) * DIM + 8 * chunk;
        rowB[r] = ((size_t)b * TOK + 2 * (tb * 128 + m)    ) * DIM + 8 * chunk;
    }

#pragma unroll 1
    for (int ks = 0; ks < 8; ++ks) {
        int col0 = ks << 6;
        STAGE4(x, x, L0, col0)
        __syncthreads();   // drains vmcnt(0): tiles ready
        COMPUTE_STEP(L0)
        __syncthreads();   // protect LDS before restage
    }

    float invd[4];
#pragma unroll
    for (int j = 0; j < 4; ++j) {
        int t = tb * 128 + wc * 64 + j * 16 + rm;
        invd[j] = invn[(size_t)b * TOK + 2 * t];
    }
#pragma unroll
    for (int i = 0; i < 4; ++i) {
#pragma unroll
        for (int r = 0; r < 4; ++r) {
            int s = sb * 128 + wr * 64 + i * 16 + cc * 4 + r;   // C row = (lane>>4)*4 + reg
            float invs = invn[(size_t)b * TOK + 2 * s + 1];
            u64 key = 0;
#pragma unroll
            for (int j = 0; j < 4; ++j) {
                int t = tb * 128 + wc * 64 + j * 16 + rm;       // C col = lane&15
                float sc = acc[i][j][r] * invs * invd[j];
                u64 k = ((u64)mono_f32(sc) << 32) | (u32)(2047 - t);
                key = umax64(key, k);
            }
#pragma unroll
            for (int m = 1; m < 16; m <<= 1) {
                u32 lo = (u32)key, hi = (u32)(key >> 32);
                lo = __shfl_xor(lo, m, 64);
                hi = __shfl_xor(hi, m, 64);
                key = umax64(key, ((u64)hi << 32) | lo);
            }
            if (rm == 0) atomicMax(&best[b * HALF + s], key);
        }
    }
}

// ---------------- top-k + duplicate-dst winner ----------------
__global__ void k_topk(const u64* __restrict__ best, u64* __restrict__ wkey,
                       u32* __restrict__ member, u32* __restrict__ dstmap) {
    __shared__ u32 smono[HALF];
    int b = blockIdx.x >> 4, sc = blockIdx.x & 15;
    int tid = threadIdx.x;
#pragma unroll
    for (int r = 0; r < 8; ++r) { int s = r * 256 + tid; smono[s] = (u32)(best[b * HALF + s] >> 32); }
    __syncthreads();
    int s = sc * 128 + (tid >> 1);
    u32 ms = smono[s];
    int t0 = (tid & 1) * 1024;
    int cnt = 0;
    for (int t = t0; t < t0 + 1024; ++t) {
        u32 mt = smono[t];
        cnt += ((mt > ms) || (mt == ms && t < s)) ? 1 : 0;
    }
    int oth = __shfl_xor(cnt, 1, 64);
    if ((tid & 1) == 0) {
        int rank = cnt + oth;
        u64 k = best[b * HALF + s];
        u32 d = 2047u - (u32)(k & 0xffffffffu);
        dstmap[b * HALF + s] = d;
        u32 mem = (rank < RR) ? 1u : 0u;
        member[b * HALF + s] = mem;
        if (mem) {
            u64 key = (k & 0xffffffff00000000ull) | (u32)(2047 - s);
            atomicMin(&wkey[b * HALF + d], key);   // last-wins: lowest score, then largest s
        }
    }
}

// ---------------- merged dst rows -> split((dst+src)/2) ----------------
__global__ void k_merge2(const float* __restrict__ x, const u64* __restrict__ wkey,
                         f16* __restrict__ xh, f16* __restrict__ xl) {
    int idx = blockIdx.x;
    int b = idx >> 11, d = idx & (HALF - 1);
    u64 wk = wkey[b * HALF + d];
    if (wk == ~0ull) return;
    int s = 2047 - (int)(wk & 0xffffffffu);
    const float* xd = x + ((size_t)b * TOK + 2 * d) * DIM;
    const float* xs = x + ((size_t)b * TOK + 2 * s + 1) * DIM;
    int l0 = threadIdx.x * 8;
    f16x8 h, l;
#pragma unroll
    for (int e = 0; e < 8; ++e) {
        float v = (xd[l0 + e] + xs[l0 + e]) * 0.5f;
        f16 hh = (f16)v;
        h[e] = hh;
        l[e] = (f16)(v - (float)hh);
    }
    size_t off = ((size_t)b * TOK + 2 * d) * DIM + l0;
    *(f16x8*)(xh + off) = h;
    *(f16x8*)(xl + off) = l;
}

// ---------------- y = x_merged @ W + b  (merged-away src rows remapped to their dst) ----------------
__launch_bounds__(256, 2)
__global__ void k_out(const f16* __restrict__ xh, const f16* __restrict__ xl,
                      const f16* __restrict__ Wh, const f16* __restrict__ Wl,
                      const float* __restrict__ bias, const u32* __restrict__ member,
                      const u32* __restrict__ dstmap, float* __restrict__ out) {
    __shared__ __align__(16) f16 L[4][128][64];   // 64 KB
    int bx = blockIdx.x;
    int im = bx >> 2, in = bx & 3;
    int tid = threadIdx.x, lane = tid & 63, w = tid >> 6, wr = w >> 1, wc = w & 1;
    int cc = lane >> 4, rm = lane & 15, rm7 = rm & 7;
    f16* L0 = &L[0][0][0];

    f32x4 acc[4][4];
#pragma unroll
    for (int i = 0; i < 4; ++i)
#pragma unroll
        for (int j = 0; j < 4; ++j) acc[i][j] = (f32x4){0.f, 0.f, 0.f, 0.f};

    size_t rowA[4], rowB[4];
#pragma unroll
    for (int r = 0; r < 4; ++r) {
        int g = tid + 256 * r;
        int m = g >> 3;
        int chunk = (g & 7) ^ (m & 7);
        int grow = im * 128 + m;
        int b_ = grow >> 12, tok = grow & (TOK - 1);
        // merged-away src row: stage its dst's merged x instead (result == dvals copy)
        if (tok & 1) {
            int s = tok >> 1;
            if (member[b_ * HALF + s]) tok = 2 * (int)dstmap[b_ * HALF + s];
        }
        rowA[r] = (((size_t)b_ << 12) + tok) * DIM + 8 * chunk;
        rowB[r] = (size_t)(in * 128 + m) * DIM + 8 * chunk;
    }

#pragma unroll 1
    for (int ks = 0; ks < 8; ++ks) {
        int col0 = ks << 6;
        STAGE4(x, W, L0, col0)
        __syncthreads();
        COMPUTE_STEP(L0)
        __syncthreads();
    }

    float bj[4];
#pragma unroll
    for (int j = 0; j < 4; ++j) bj[j] = bias[in * 128 + wc * 64 + j * 16 + rm];
#pragma unroll
    for (int i = 0; i < 4; ++i) {
#pragma unroll
        for (int r = 0; r < 4; ++r) {
            int gm = im * 128 + wr * 64 + i * 16 + cc * 4 + r;
#pragma unroll
            for (int j = 0; j < 4; ++j) {
                int n = in * 128 + wc * 64 + j * 16 + rm;
                out[(size_t)gm * DIM + n] = acc[i][j][r] + bj[j];
            }
        }
    }
}

extern "C" void kernel_launch(void* const* d_in, const int* in_sizes, int n_in,
                              void* d_out, int out_size, void* d_ws, size_t ws_size,
                              hipStream_t stream) {
    const float* x    = (const float*)d_in[0];
    const float* W    = (const float*)d_in[1];
    const float* bias = (const float*)d_in[2];
    float* out = (float*)d_out;

    char* ws = (char*)d_ws;
    f16*   xh     = (f16*)(ws);                               // 32 MB
    f16*   xl     = (f16*)(ws + (32u << 20));                 // 32 MB
    f16*   Wh     = (f16*)(ws + (64u << 20));                 // 512 KB
    f16*   Wl     = (f16*)(ws + (64u << 20) + (512u << 10));  // 512 KB
    float* invn   = (float*)(ws + (65u << 20));               // 128 KB
    u64*   best   = (u64*)(ws + (65u << 20) + (128u << 10));  // 128 KB
    u64*   wkey   = (u64*)(ws + (65u << 20) + (256u << 10));  // 128 KB
    u32*   dstmap = (u32*)(ws + (65u << 20) + (384u << 10));  //  64 KB
    u32*   member = (u32*)(ws + (65u << 20) + (448u << 10));  //  64 KB

    hipLaunchKernelGGL(k_pre,    dim3(8320),  dim3(256), 0, stream, x, xh, xl, invn, W, Wh, Wl, best, wkey);
    hipLaunchKernelGGL(k_scores, dim3(2048),  dim3(256), 0, stream, xh, xl, invn, best);
    hipLaunchKernelGGL(k_topk,   dim3(128),   dim3(256), 0, stream, best, wkey, member, dstmap);
    hipLaunchKernelGGL(k_merge2, dim3(16384), dim3(64),  0, stream, x, wkey, xh, xl);
    hipLaunchKernelGGL(k_out,    dim3(1024),  dim3(256), 0, stream, xh, xl, Wh, Wl, bias, member, dstmap, out);
}